// Round 1
// baseline (993.201 us; speedup 1.0000x reference)
//
#include <hip/hip_runtime.h>
#include <hip/hip_bf16.h>
#include <cstdint>

// CausalSelfAttention: B=2, L=2048, D=1024, H=16, dh=64 (fp32 in/out).
// Round 0: correct fp32 baseline.
//   k1: kq  = x @ W_kq + b_kq   (4096 x 2048 x 1024)   -> ws
//   k2: v   = x @ W_v  + b_v    (4096 x 1024 x 1024)   -> ws
//   k3: att = causal flash attention (online softmax)  -> ws
//   k4: out = att @ W_o + b_o   (4096 x 1024 x 1024)   -> d_out
// GEMM: 64x64 C tile, BK=16, 256 thr, 4x4 microtile, LDS float4 reads.
// Attention: 64 q-rows per block, K/P union LDS buffer (52 KB total).

#define LSEQ 2048
#define DM   1024
#define DH   64
#define NH   16

__global__ __launch_bounds__(256) void gemm_bias_kernel(
    const float* __restrict__ A, const float* __restrict__ B,
    const float* __restrict__ bias, float* __restrict__ C,
    int M, int N, int K)
{
    const int tid = threadIdx.x;
    const int tx  = tid & 15;   // N direction
    const int ty  = tid >> 4;   // M direction
    const int n0  = blockIdx.x * 64;
    const int m0  = blockIdx.y * 64;

    __shared__ float As[16][68];   // [kk][m], transposed on store
    __shared__ float Bs[16][68];   // [kk][n]

    const int a_row = tid >> 2;          // 0..63
    const int a_col = (tid & 3) << 2;    // 0,4,8,12
    const int b_row = tid >> 4;          // 0..15
    const int b_col = (tid & 15) << 2;   // 0..60

    const float* Aptr = A + (size_t)(m0 + a_row) * K + a_col;
    const float* Bptr = B + (size_t)b_row * N + n0 + b_col;

    float acc[4][4] = {{0.f,0.f,0.f,0.f},{0.f,0.f,0.f,0.f},
                       {0.f,0.f,0.f,0.f},{0.f,0.f,0.f,0.f}};

    for (int k0 = 0; k0 < K; k0 += 16) {
        const float4 av = *(const float4*)(Aptr + k0);
        const float4 bv = *(const float4*)(Bptr + (size_t)k0 * N);
        __syncthreads();
        As[a_col + 0][a_row] = av.x;
        As[a_col + 1][a_row] = av.y;
        As[a_col + 2][a_row] = av.z;
        As[a_col + 3][a_row] = av.w;
        *(float4*)&Bs[b_row][b_col] = bv;
        __syncthreads();
#pragma unroll
        for (int kk = 0; kk < 16; ++kk) {
            const float4 a4 = *(const float4*)&As[kk][ty << 2];
            const float4 b4 = *(const float4*)&Bs[kk][tx << 2];
            const float ar[4] = {a4.x, a4.y, a4.z, a4.w};
            const float br[4] = {b4.x, b4.y, b4.z, b4.w};
#pragma unroll
            for (int i = 0; i < 4; ++i)
#pragma unroll
                for (int j = 0; j < 4; ++j)
                    acc[i][j] = fmaf(ar[i], br[j], acc[i][j]);
        }
    }

    const float4 biasv = *(const float4*)&bias[n0 + (tx << 2)];
    const float bb[4] = {biasv.x, biasv.y, biasv.z, biasv.w};
#pragma unroll
    for (int i = 0; i < 4; ++i) {
        float4 c;
        c.x = acc[i][0] + bb[0];
        c.y = acc[i][1] + bb[1];
        c.z = acc[i][2] + bb[2];
        c.w = acc[i][3] + bb[3];
        *(float4*)&C[(size_t)(m0 + (ty << 2) + i) * N + n0 + (tx << 2)] = c;
    }
}

// kq: (B*L, 2*DM) with k in [:,0:DM], q in [:,DM:2*DM]
// v:  (B*L, DM)
// att:(B*L, DM)
__global__ __launch_bounds__(256) void attn_kernel(
    const float* __restrict__ kq, const float* __restrict__ vbuf,
    float* __restrict__ att)
{
    const int tid = threadIdx.x;
    const int tx  = tid & 15;   // key / d direction
    const int ty  = tid >> 4;   // q-row direction
    const int qt  = 31 - blockIdx.x;      // heavy q-tiles first
    const int bh  = blockIdx.y;
    const int b   = bh >> 4;
    const int h   = bh & 15;
    const int q0  = qt * 64;

    __shared__ float Qst[DH][68];   // [d][qrow]
    __shared__ float KP [DH][68];   // K phase: [d][krow]; P phase: [krow][qrow]
    __shared__ float Vs [64][68];   // [krow][d]

    // cooperative load mapping: 4 threads per row, 4 float4 each
    const int lrow  = tid >> 2;          // 0..63
    const int dbase = (tid & 3) << 4;    // 0,16,32,48

    // load Q tile (transposed into Qst)
    {
        const float* qptr = kq + (size_t)(b * LSEQ + q0 + lrow) * (2 * DM)
                               + DM + h * DH + dbase;
#pragma unroll
        for (int i = 0; i < 4; ++i) {
            const float4 t = *(const float4*)(qptr + i * 4);
            Qst[dbase + i * 4 + 0][lrow] = t.x;
            Qst[dbase + i * 4 + 1][lrow] = t.y;
            Qst[dbase + i * 4 + 2][lrow] = t.z;
            Qst[dbase + i * 4 + 3][lrow] = t.w;
        }
    }

    float O[4][4] = {{0.f,0.f,0.f,0.f},{0.f,0.f,0.f,0.f},
                     {0.f,0.f,0.f,0.f},{0.f,0.f,0.f,0.f}};
    float m[4] = {-1e30f, -1e30f, -1e30f, -1e30f};
    float l[4] = {0.f, 0.f, 0.f, 0.f};
    const float scale = 0.125f;   // 1/sqrt(64)

    for (int kt = 0; kt <= qt; ++kt) {
        const int k0 = kt * 64;
        __syncthreads();   // previous iter done with KP/Vs (and Q-load visible)
        {
            const float* kptr = kq + (size_t)(b * LSEQ + k0 + lrow) * (2 * DM)
                                   + h * DH + dbase;
            const float* vptr = vbuf + (size_t)(b * LSEQ + k0 + lrow) * DM
                                     + h * DH + dbase;
#pragma unroll
            for (int i = 0; i < 4; ++i) {
                const float4 t = *(const float4*)(kptr + i * 4);
                KP[dbase + i * 4 + 0][lrow] = t.x;
                KP[dbase + i * 4 + 1][lrow] = t.y;
                KP[dbase + i * 4 + 2][lrow] = t.z;
                KP[dbase + i * 4 + 3][lrow] = t.w;
                *(float4*)&Vs[lrow][dbase + i * 4] = *(const float4*)(vptr + i * 4);
            }
        }
        __syncthreads();

        // S = Q @ K^T  (thread: rows ty*4+ii, key cols tx*4+jj)
        float S[4][4] = {{0.f,0.f,0.f,0.f},{0.f,0.f,0.f,0.f},
                         {0.f,0.f,0.f,0.f},{0.f,0.f,0.f,0.f}};
#pragma unroll 8
        for (int d = 0; d < DH; ++d) {
            const float4 a4 = *(const float4*)&Qst[d][ty << 2];
            const float4 b4 = *(const float4*)&KP[d][tx << 2];
            const float ar[4] = {a4.x, a4.y, a4.z, a4.w};
            const float br[4] = {b4.x, b4.y, b4.z, b4.w};
#pragma unroll
            for (int i = 0; i < 4; ++i)
#pragma unroll
                for (int j = 0; j < 4; ++j)
                    S[i][j] = fmaf(ar[i], br[j], S[i][j]);
        }
#pragma unroll
        for (int i = 0; i < 4; ++i)
#pragma unroll
            for (int j = 0; j < 4; ++j)
                S[i][j] *= scale;
        if (kt == qt) {   // diagonal tile: causal mask
#pragma unroll
            for (int i = 0; i < 4; ++i)
#pragma unroll
                for (int j = 0; j < 4; ++j)
                    if (((tx << 2) + j) > ((ty << 2) + i)) S[i][j] = -1e30f;
        }

        // online softmax (row groups = 16 contiguous lanes in-wave)
#pragma unroll
        for (int i = 0; i < 4; ++i) {
            float mloc = fmaxf(fmaxf(S[i][0], S[i][1]), fmaxf(S[i][2], S[i][3]));
#pragma unroll
            for (int off = 8; off >= 1; off >>= 1)
                mloc = fmaxf(mloc, __shfl_xor(mloc, off));
            const float mnew  = fmaxf(m[i], mloc);
            const float alpha = __expf(m[i] - mnew);
            float rsum = 0.f;
#pragma unroll
            for (int j = 0; j < 4; ++j) {
                S[i][j] = __expf(S[i][j] - mnew);
                rsum += S[i][j];
            }
#pragma unroll
            for (int off = 8; off >= 1; off >>= 1)
                rsum += __shfl_xor(rsum, off);
            l[i] = l[i] * alpha + rsum;
            m[i] = mnew;
#pragma unroll
            for (int d = 0; d < 4; ++d) O[i][d] *= alpha;
        }

        // write P transposed into KP: P[j][qrow]
        __syncthreads();
#pragma unroll
        for (int i = 0; i < 4; ++i)
#pragma unroll
            for (int j = 0; j < 4; ++j)
                KP[(tx << 2) + j][(ty << 2) + i] = S[i][j];
        __syncthreads();

        // O += P @ V   (thread: rows ty*4+ii, d cols tx*4+dd)
#pragma unroll 8
        for (int j = 0; j < 64; ++j) {
            const float4 a4 = *(const float4*)&KP[j][ty << 2];
            const float4 b4 = *(const float4*)&Vs[j][tx << 2];
            const float ar[4] = {a4.x, a4.y, a4.z, a4.w};
            const float br[4] = {b4.x, b4.y, b4.z, b4.w};
#pragma unroll
            for (int i = 0; i < 4; ++i)
#pragma unroll
                for (int d = 0; d < 4; ++d)
                    O[i][d] = fmaf(ar[i], br[d], O[i][d]);
        }
    }

    // epilogue: O / l -> att
#pragma unroll
    for (int i = 0; i < 4; ++i) {
        const float inv = 1.0f / l[i];
        float4 o;
        o.x = O[i][0] * inv;
        o.y = O[i][1] * inv;
        o.z = O[i][2] * inv;
        o.w = O[i][3] * inv;
        const size_t idx = (size_t)(b * LSEQ + q0 + (ty << 2) + i) * DM
                         + h * DH + (tx << 2);
        *(float4*)&att[idx] = o;
    }
}

extern "C" void kernel_launch(void* const* d_in, const int* in_sizes, int n_in,
                              void* d_out, int out_size, void* d_ws, size_t ws_size,
                              hipStream_t stream)
{
    const float* x    = (const float*)d_in[0];
    const float* W_kq = (const float*)d_in[1];
    const float* b_kq = (const float*)d_in[2];
    const float* W_v  = (const float*)d_in[3];
    const float* b_v  = (const float*)d_in[4];
    const float* W_o  = (const float*)d_in[5];
    const float* b_o  = (const float*)d_in[6];
    float* out = (float*)d_out;

    const int B  = in_sizes[0] / (LSEQ * DM);   // = 2
    const int BL = B * LSEQ;                    // = 4096

    float* kq  = (float*)d_ws;                          // BL * 2048
    float* v   = kq + (size_t)BL * 2 * DM;              // BL * 1024
    float* att = v  + (size_t)BL * DM;                  // BL * 1024

    // kq = x @ W_kq + b_kq
    gemm_bias_kernel<<<dim3((2 * DM) / 64, BL / 64), 256, 0, stream>>>(
        x, W_kq, b_kq, kq, BL, 2 * DM, DM);
    // v = x @ W_v + b_v
    gemm_bias_kernel<<<dim3(DM / 64, BL / 64), 256, 0, stream>>>(
        x, W_v, b_v, v, BL, DM, DM);
    // attention
    attn_kernel<<<dim3(LSEQ / 64, B * NH), 256, 0, stream>>>(kq, v, att);
    // out = att @ W_o + b_o
    gemm_bias_kernel<<<dim3(DM / 64, BL / 64), 256, 0, stream>>>(
        att, W_o, b_o, out, BL, DM, DM);
}

// Round 2
// 228.761 us; speedup vs baseline: 4.3417x; 4.3417x over previous
//
#include <hip/hip_runtime.h>
#include <cstdint>

// CausalSelfAttention B=2 L=2048 D=1024 H=16 dh=64, fp32 in/out.
// Round 2: full bf16-MFMA pipeline.
//   prep : x -> bf16 ; W_kq/W_v/W_o -> transposed bf16 (N x K)
//   g1   : kq  = xb @ Wkq^T + b   -> bf16 [4096 x 2048]     (mode 1)
//   g2   : v^T = (xb @ Wv^T + b)^T -> bf16 [1024 x 4096]    (mode 2)
//   attn : flash MFMA, online softmax -> att bf16 [4096x1024]
//   g3   : out = att @ Wo^T + b -> fp32 d_out               (mode 0)
// GEMM: 128x128 tile, BK=64, global_load_lds width 16, XOR chunk swizzle.

#define LSEQ 2048
#define DM   1024
#define BL   4096   // B * LSEQ

using frag_ab = __attribute__((ext_vector_type(8))) short;  // 8 bf16
using f32x4   = __attribute__((ext_vector_type(4))) float;

__device__ __forceinline__ unsigned short f2bf(float f) {
  unsigned int u = __float_as_uint(f);
  u += 0x7fffu + ((u >> 16) & 1u);   // RNE (finite inputs only)
  return (unsigned short)(u >> 16);
}

__device__ __forceinline__ void load_lds16(const void* g, void* l) {
  __builtin_amdgcn_global_load_lds(
      (const __attribute__((address_space(1))) unsigned int*)g,
      (__attribute__((address_space(3))) unsigned int*)l, 16, 0, 0);
}

// ---------------- prep kernels ----------------

__global__ __launch_bounds__(256) void cast_bf16_kernel(
    const float* __restrict__ in, unsigned short* __restrict__ out, int n4)
{
  int i = (blockIdx.x * 256 + threadIdx.x);
  if (i < n4) {
    const float4 v = *(const float4*)&in[i * 4];
    ushort4 o;
    o.x = f2bf(v.x); o.y = f2bf(v.y); o.z = f2bf(v.z); o.w = f2bf(v.w);
    *(ushort4*)&out[i * 4] = o;
  }
}

// W (K x N fp32) -> Wt (N x K bf16)
__global__ __launch_bounds__(256) void transpose_cast_kernel(
    const float* __restrict__ W, unsigned short* __restrict__ Wt, int K, int N)
{
  __shared__ float tile[32][33];
  const int r  = threadIdx.x >> 3;        // 0..31
  const int c4 = (threadIdx.x & 7) * 4;   // 0..28
  const int kb = blockIdx.y * 32;
  const int nb = blockIdx.x * 32;

  const float4 v = *(const float4*)&W[(size_t)(kb + r) * N + nb + c4];
  tile[r][c4 + 0] = v.x; tile[r][c4 + 1] = v.y;
  tile[r][c4 + 2] = v.z; tile[r][c4 + 3] = v.w;
  __syncthreads();
  ushort4 o;
  o.x = f2bf(tile[c4 + 0][r]);
  o.y = f2bf(tile[c4 + 1][r]);
  o.z = f2bf(tile[c4 + 2][r]);
  o.w = f2bf(tile[c4 + 3][r]);
  *(ushort4*)&Wt[(size_t)(nb + r) * K + kb + c4] = o;
}

// ---------------- GEMM: C = A(MxK) @ Bt(NxK)^T + bias ----------------
// MODE 0: fp32 C ; MODE 1: bf16 C ; MODE 2: bf16 C^T (ld = ldT)

template <int MODE>
__global__ __launch_bounds__(256) void gemm_mfma(
    const unsigned short* __restrict__ A, const unsigned short* __restrict__ Bt,
    const float* __restrict__ bias, void* __restrict__ Cout,
    int M, int N, int K, int ldT)
{
  const int tid  = threadIdx.x;
  const int lane = tid & 63;
  const int w    = tid >> 6;
  const int wm   = (w >> 1) * 64;
  const int wn   = (w & 1) * 64;
  const int n0   = blockIdx.x * 128;
  const int m0   = blockIdx.y * 128;
  const int quad = lane >> 4;
  const int l15  = lane & 15;

  __shared__ __align__(16) unsigned short As[128 * 64];
  __shared__ __align__(16) unsigned short Bs[128 * 64];

  const int srow = lane >> 3;            // 0..7
  const int sc   = (lane & 7) ^ srow;    // swizzled global chunk

  const unsigned short* gA = A  + (size_t)(m0 + w * 32 + srow) * K + sc * 8;
  const unsigned short* gB = Bt + (size_t)(n0 + w * 32 + srow) * K + sc * 8;

  f32x4 acc[4][4] = {};

  for (int k0 = 0; k0 < K; k0 += 64) {
    __syncthreads();
#pragma unroll
    for (int i = 0; i < 4; ++i) {
      load_lds16(gA + (size_t)i * 8 * K + k0, &As[(w * 32 + i * 8) * 64 + lane * 8]);
      load_lds16(gB + (size_t)i * 8 * K + k0, &Bs[(w * 32 + i * 8) * 64 + lane * 8]);
    }
    __syncthreads();
#pragma unroll
    for (int kf = 0; kf < 2; ++kf) {
      frag_ab af[4], bf[4];
#pragma unroll
      for (int t = 0; t < 4; ++t) {
        const int ra = wm + t * 16 + l15;
        const int pa = (kf * 4 + quad) ^ (ra & 7);
        af[t] = *(const frag_ab*)&As[ra * 64 + pa * 8];
        const int rb = wn + t * 16 + l15;
        const int pb = (kf * 4 + quad) ^ (rb & 7);
        bf[t] = *(const frag_ab*)&Bs[rb * 64 + pb * 8];
      }
#pragma unroll
      for (int i = 0; i < 4; ++i)
#pragma unroll
        for (int j = 0; j < 4; ++j)
          acc[i][j] = __builtin_amdgcn_mfma_f32_16x16x32_bf16(
              af[i], bf[j], acc[i][j], 0, 0, 0);
    }
  }

#pragma unroll
  for (int i = 0; i < 4; ++i) {
#pragma unroll
    for (int j = 0; j < 4; ++j) {
      const int row0 = m0 + wm + i * 16 + quad * 4;
      const int col  = n0 + wn + j * 16 + l15;
      const float bv = bias[col];
      if (MODE == 0) {
        float* C = (float*)Cout;
#pragma unroll
        for (int r = 0; r < 4; ++r)
          C[(size_t)(row0 + r) * N + col] = acc[i][j][r] + bv;
      } else if (MODE == 1) {
        unsigned short* C = (unsigned short*)Cout;
#pragma unroll
        for (int r = 0; r < 4; ++r)
          C[(size_t)(row0 + r) * N + col] = f2bf(acc[i][j][r] + bv);
      } else {
        unsigned short* C = (unsigned short*)Cout;
        ushort4 pk;
        pk.x = f2bf(acc[i][j][0] + bv);
        pk.y = f2bf(acc[i][j][1] + bv);
        pk.z = f2bf(acc[i][j][2] + bv);
        pk.w = f2bf(acc[i][j][3] + bv);
        *(ushort4*)&C[(size_t)col * ldT + row0] = pk;
      }
    }
  }
}

// ---------------- flash attention (MFMA) ----------------
// kq: bf16 [BL][2048] (k at col 0, q at col 1024); vt: bf16 [1024][BL]
// att: bf16 [BL][1024]

__global__ __launch_bounds__(256) void attn_mfma(
    const unsigned short* __restrict__ kq, const unsigned short* __restrict__ vt,
    unsigned short* __restrict__ att)
{
  const int tid  = threadIdx.x;
  const int lane = tid & 63;
  const int w    = tid >> 6;
  const int bx   = blockIdx.x;
  const int qt   = 31 - (bx >> 5);   // heavy q-tiles first
  const int bh   = bx & 31;
  const int b    = bh >> 4;
  const int h    = bh & 15;
  const int q0   = qt * 64;
  const int quad = lane >> 4;
  const int l15  = lane & 15;

  __shared__ __align__(16) unsigned short Qs[64 * 64];
  __shared__ __align__(16) unsigned short Ks[64 * 64];
  __shared__ __align__(16) unsigned short Vs[64 * 64];
  __shared__ __align__(16) unsigned short Ps[4 * 16 * 64];

  const int srow = lane >> 3;
  const int sc   = (lane & 7) ^ srow;

  // stage Q once (rows = q in tile, 64 bf16 = 8 chunks, swizzled)
#pragma unroll
  for (int i = 0; i < 2; ++i) {
    const int j = w * 2 + i;
    const int row = j * 8 + srow;
    const unsigned short* g =
        kq + (size_t)(b * LSEQ + q0 + row) * (2 * DM) + DM + h * 64 + sc * 8;
    load_lds16(g, &Qs[j * 8 * 64 + lane * 8]);
  }

  f32x4 oacc[4] = {};
  float mrow[4] = {-3e38f, -3e38f, -3e38f, -3e38f};
  float lrow[4] = {0.f, 0.f, 0.f, 0.f};
  const float scale = 0.125f;   // 1/sqrt(64)

  for (int kt = 0; kt <= qt; ++kt) {
    const int k0 = kt * 64;
    __syncthreads();   // prev iter done with Ks/Vs/Ps
#pragma unroll
    for (int i = 0; i < 2; ++i) {
      const int j = w * 2 + i;
      const int row = j * 8 + srow;
      const unsigned short* gk =
          kq + (size_t)(b * LSEQ + k0 + row) * (2 * DM) + h * 64 + sc * 8;
      load_lds16(gk, &Ks[j * 8 * 64 + lane * 8]);
      const unsigned short* gv =
          vt + (size_t)(h * 64 + row) * BL + b * LSEQ + k0 + sc * 8;
      load_lds16(gv, &Vs[j * 8 * 64 + lane * 8]);
    }
    __syncthreads();   // vmcnt(0) drained -> tiles visible

    // S = Q @ K^T  (wave w: q rows w*16..w*16+15, all 64 keys)
    frag_ab qa[2];
#pragma unroll
    for (int kf = 0; kf < 2; ++kf) {
      const int row = w * 16 + l15;
      const int p = (kf * 4 + quad) ^ (row & 7);
      qa[kf] = *(const frag_ab*)&Qs[row * 64 + p * 8];
    }
    f32x4 S[4];
#pragma unroll
    for (int nt = 0; nt < 4; ++nt) {
      f32x4 s = {};
#pragma unroll
      for (int kf = 0; kf < 2; ++kf) {
        const int row = nt * 16 + l15;
        const int p = (kf * 4 + quad) ^ (row & 7);
        const frag_ab kb = *(const frag_ab*)&Ks[row * 64 + p * 8];
        s = __builtin_amdgcn_mfma_f32_16x16x32_bf16(qa[kf], kb, s, 0, 0, 0);
      }
      S[nt] = s;
    }

    // scale + causal mask (only the diagonal tile needs masking)
#pragma unroll
    for (int nt = 0; nt < 4; ++nt)
#pragma unroll
      for (int r = 0; r < 4; ++r) {
        float v = S[nt][r] * scale;
        if (kt == qt && (nt * 16 + l15) > (w * 16 + quad * 4 + r)) v = -3e38f;
        S[nt][r] = v;
      }

    // online softmax per q-row; write P (bf16) in A-operand layout
#pragma unroll
    for (int r = 0; r < 4; ++r) {
      float smax = fmaxf(fmaxf(S[0][r], S[1][r]), fmaxf(S[2][r], S[3][r]));
#pragma unroll
      for (int off = 8; off >= 1; off >>= 1)
        smax = fmaxf(smax, __shfl_xor(smax, off));
      const float mnew  = fmaxf(mrow[r], smax);
      const float alpha = __expf(mrow[r] - mnew);
      float ev[4];
      float rsum = 0.f;
#pragma unroll
      for (int nt = 0; nt < 4; ++nt) { ev[nt] = __expf(S[nt][r] - mnew); rsum += ev[nt]; }
#pragma unroll
      for (int off = 8; off >= 1; off >>= 1)
        rsum += __shfl_xor(rsum, off);
      lrow[r] = lrow[r] * alpha + rsum;
      mrow[r] = mnew;
#pragma unroll
      for (int nt = 0; nt < 4; ++nt) oacc[nt][r] *= alpha;
      const int q = quad * 4 + r;   // q-row within wave's 16
#pragma unroll
      for (int nt = 0; nt < 4; ++nt) {
        const int key = nt * 16 + l15;
        const int p = (key >> 3) ^ (q & 7);
        Ps[w * 1024 + q * 64 + p * 8 + (key & 7)] = f2bf(ev[nt]);
      }
    }
    __syncthreads();   // P visible

    // O += P @ V   (B-operand from Vt rows = dh)
    frag_ab pa[2];
#pragma unroll
    for (int kf = 0; kf < 2; ++kf) {
      const int p = (kf * 4 + quad) ^ (l15 & 7);
      pa[kf] = *(const frag_ab*)&Ps[w * 1024 + l15 * 64 + p * 8];
    }
#pragma unroll
    for (int nt = 0; nt < 4; ++nt) {
#pragma unroll
      for (int kf = 0; kf < 2; ++kf) {
        const int row = nt * 16 + l15;
        const int p = (kf * 4 + quad) ^ (row & 7);
        const frag_ab vb = *(const frag_ab*)&Vs[row * 64 + p * 8];
        oacc[nt] = __builtin_amdgcn_mfma_f32_16x16x32_bf16(pa[kf], vb, oacc[nt], 0, 0, 0);
      }
    }
  }

  // epilogue: O / l -> att (bf16)
#pragma unroll
  for (int r = 0; r < 4; ++r) {
    const float inv = 1.0f / lrow[r];
    const int row = b * LSEQ + q0 + w * 16 + quad * 4 + r;
#pragma unroll
    for (int nt = 0; nt < 4; ++nt) {
      const int col = h * 64 + nt * 16 + l15;
      att[(size_t)row * DM + col] = f2bf(oacc[nt][r] * inv);
    }
  }
}

// ---------------- launcher ----------------

extern "C" void kernel_launch(void* const* d_in, const int* in_sizes, int n_in,
                              void* d_out, int out_size, void* d_ws, size_t ws_size,
                              hipStream_t stream)
{
  const float* x    = (const float*)d_in[0];
  const float* W_kq = (const float*)d_in[1];
  const float* b_kq = (const float*)d_in[2];
  const float* W_v  = (const float*)d_in[3];
  const float* b_v  = (const float*)d_in[4];
  const float* W_o  = (const float*)d_in[5];
  const float* b_o  = (const float*)d_in[6];

  unsigned short* ws   = (unsigned short*)d_ws;
  unsigned short* xb   = ws;                    // 4096*1024
  unsigned short* wkqt = xb   + 4194304;        // 2048*1024
  unsigned short* wvt  = wkqt + 2097152;        // 1024*1024
  unsigned short* wot  = wvt  + 1048576;        // 1024*1024
  unsigned short* kqb  = wot  + 1048576;        // 4096*2048
  unsigned short* vtb  = kqb  + 8388608;        // 1024*4096
  unsigned short* attb = vtb  + 4194304;        // 4096*1024

  cast_bf16_kernel<<<4096, 256, 0, stream>>>(x, xb, 1048576);
  transpose_cast_kernel<<<dim3(64, 32), 256, 0, stream>>>(W_kq, wkqt, 1024, 2048);
  transpose_cast_kernel<<<dim3(32, 32), 256, 0, stream>>>(W_v,  wvt,  1024, 1024);
  transpose_cast_kernel<<<dim3(32, 32), 256, 0, stream>>>(W_o,  wot,  1024, 1024);

  // kq = xb @ Wkq^T + b_kq  -> bf16 [4096 x 2048]
  gemm_mfma<1><<<dim3(16, 32), 256, 0, stream>>>(xb, wkqt, b_kq, kqb,
                                                 BL, 2048, 1024, 0);
  // v^T = (xb @ Wv^T + b_v)^T -> bf16 [1024 x 4096]
  gemm_mfma<2><<<dim3(8, 32), 256, 0, stream>>>(xb, wvt, b_v, vtb,
                                                BL, 1024, 1024, BL);
  // attention
  attn_mfma<<<1024, 256, 0, stream>>>(kqb, vtb, attb);
  // out = att @ Wo^T + b_o -> fp32
  gemm_mfma<0><<<dim3(8, 32), 256, 0, stream>>>(attb, wot, b_o, (float*)d_out,
                                                BL, 1024, 1024, 0);
}